// Round 3
// baseline (205.659 us; speedup 1.0000x reference)
//
#include <hip/hip_runtime.h>
#include <math.h>

#define B 32
#define Q 10000
#define C 80
#define TOPK 200

// ---------------------------------------------------------------------------
// Fast double-precision exp for x in [-40, 0]  (identical bits to R2 version)
// ---------------------------------------------------------------------------
__device__ __forceinline__ double fexp(double x) {
    const double L2E   = 1.4426950408889634;      // log2(e)
    const double SHIFT = 6755399441055744.0;      // 1.5 * 2^52
    const double LN2   = 0.6931471805599453;

    double y = x * L2E;
    double t = y + SHIFT;
    union { double d; unsigned long long u; } cv;
    cv.d = t;
    int n = (int)(unsigned int)cv.u;              // low 32 bits = rint(y)
    double f = y - (t - SHIFT);                   // f in [-0.5, 0.5]
    double r = f * LN2;

    double p = 2.755731922398589e-06;             // 1/9!
    p = fma(p, r, 2.4801587301587302e-05);
    p = fma(p, r, 1.984126984126984e-04);
    p = fma(p, r, 1.3888888888888889e-03);
    p = fma(p, r, 8.333333333333333e-03);
    p = fma(p, r, 4.1666666666666664e-02);
    p = fma(p, r, 1.6666666666666666e-01);
    p = fma(p, r, 0.5);
    p = fma(p, r, 1.0);
    p = fma(p, r, 1.0);

    cv.d = p;
    cv.u += ((unsigned long long)(long long)n) << 52;
    return cv.d;
}

// ---------------------------------------------------------------------------
// Per-row scoring: EXACT same expression sequence as the proven bit-exact
// version (strict-> max, sequential double sum, float cast, reciprocal).
// ---------------------------------------------------------------------------
__device__ __forceinline__ void score_row(const float* __restrict__ row,
                                          int grow,
                                          unsigned long long* __restrict__ keys,
                                          int* __restrict__ cls_out)
{
    float m = -INFINITY; int idx = 0;
#pragma unroll 8
    for (int j = 0; j < 80; ++j) {
        float v = row[j];
        if (v > m) { m = v; idx = j; }               // strict >: first occurrence
    }

    const double md = (double)m;
    double s = 0.0;
#pragma unroll 8
    for (int j = 0; j < 80; ++j)
        s += fexp((double)row[j] - md);              // sequential order == R2

    float sumf  = (float)s;
    float score = 1.0f / sumf;
    unsigned int sbits = __float_as_uint(score);
    unsigned int q = (unsigned)(grow % Q);
    keys[grow]    = ((unsigned long long)sbits << 32) |
                    (unsigned long long)(0xFFFFFFFFu - q);
    cls_out[grow] = idx;
}

// ---------------------------------------------------------------------------
// Kernel 1 v4: 2-tile register-prefetch double buffer.
// Each 64-thread block owns 128 rows (two 64-row tiles). Tile 0 is staged to
// LDS (stride 81 dwords -> conflict-free), tile 1's 20 dwordx4 loads are
// ISSUED into registers before the tile-0 FP64 loop; a sched_barrier pins the
// LDS writes after the compute, so the HBM latency of tile 1 hides under
// tile 0's ~5100-cycle fexp chain. Numerics per row are bit-identical.
// ---------------------------------------------------------------------------
__global__ __launch_bounds__(64) void score_kernel(
    const float* __restrict__ logits,
    unsigned long long* __restrict__ keys,
    int* __restrict__ cls_out)
{
    __shared__ float sb[2][64 * 81];
    const int t = threadIdx.x;                       // 0..63
    const int rowBase = blockIdx.x * 128;            // tile0 rows: rowBase..+63

    // ---- stage tile 0 into LDS (coalesced dwordx4) ----
    const float4* src0 = (const float4*)(logits + (long long)rowBase * C);
#pragma unroll
    for (int i = 0; i < 20; ++i) {
        int g = i * 64 + t;                          // float4 index in 1280-chunk
        float4 v = src0[g];
        int r = g / 20;
        int c = (g % 20) * 4;
        float* d = &sb[0][r * 81 + c];
        d[0] = v.x; d[1] = v.y; d[2] = v.z; d[3] = v.w;
    }

    // ---- issue tile 1 loads into registers (in flight during tile-0 math) ----
    const float4* src1 = (const float4*)(logits + (long long)(rowBase + 64) * C);
    float4 pf[20];
#pragma unroll
    for (int i = 0; i < 20; ++i)
        pf[i] = src1[i * 64 + t];

    __syncthreads();                                 // tile 0 visible

    // ---- compute tile 0 (long FP64 phase; tile-1 loads still in flight) ----
    score_row(&sb[0][t * 81], rowBase + t, keys, cls_out);

    // keep the ds_writes AFTER the compute phase (don't let the scheduler
    // hoist them up to the vmcnt wait and serialize the overlap)
    __builtin_amdgcn_sched_barrier(0);

    // ---- write tile 1 into its LDS buffer ----
#pragma unroll
    for (int i = 0; i < 20; ++i) {
        int g = i * 64 + t;
        int r = g / 20;
        int c = (g % 20) * 4;
        float* d = &sb[1][r * 81 + c];
        d[0] = pf[i].x; d[1] = pf[i].y; d[2] = pf[i].z; d[3] = pf[i].w;
    }
    __syncthreads();                                 // tile 1 visible

    // ---- compute tile 1 ----
    score_row(&sb[1][t * 81], rowBase + 64 + t, keys, cls_out);
}

// ---------------------------------------------------------------------------
// Kernel 2 (VERBATIM R1 — best measured config): one block (1024 threads)
// per batch. keys -> registers; 13-bit histogram -> wave-0 threshold scan;
// 11-bit refinement histogram on boundary bucket -> wave-0 scan (count
// ~200-210); ballot-aggregated collect; all-pairs rank scatter (exact sort);
// sup bitmatrix; register-resident wave-parallel greedy; compaction.
// ---------------------------------------------------------------------------
__global__ __launch_bounds__(1024) void nms_kernel(
    const unsigned long long* __restrict__ keys,
    const int*   __restrict__ classes,
    const float* __restrict__ seg,
    int*         __restrict__ out)
{
    __shared__ unsigned int        hist[2048];
    __shared__ unsigned long long  skey[2048];      // collected candidates
    __shared__ unsigned long long  skey2[TOPK];     // rank-scattered top-200
    __shared__ int   s_count;
    __shared__ unsigned int s_tb, s_acc, s_t2;
    __shared__ int   cidx[TOPK];
    __shared__ int   ccls[TOPK];
    __shared__ float cx1[TOPK], cx2[TOPK];
    __shared__ unsigned long long sup[TOPK][4];
    __shared__ int   keepArr[TOPK];
    __shared__ int   s_keepCount;

    const int b   = blockIdx.x;
    const int tid = threadIdx.x;
    const unsigned long long* bk = keys + (long long)b * Q;

    // ---- single global pass: keys into registers (10 per thread) ----
    unsigned long long kreg[10];
#pragma unroll
    for (int r = 0; r < 10; ++r) {
        int i = r * 1024 + tid;
        kreg[r] = (i < Q) ? bk[i] : 0ull;
    }

    for (int i = tid; i < 2048; i += 1024) hist[i] = 0;
    if (tid == 0) s_count = 0;
    __syncthreads();

    // ---- histogram of top 13 bits of key (== top 13 bits of score) ----
#pragma unroll
    for (int r = 0; r < 10; ++r) {
        if (r * 1024 + tid < Q)
            atomicAdd(&hist[(unsigned int)(kreg[r] >> 51)], 1u);
    }
    __syncthreads();

    // ---- level-1 threshold: wave-0 two-level suffix scan ----
    if (tid < 64) {
        int cs = 0;
#pragma unroll
        for (int k = 0; k < 32; ++k) cs += (int)hist[tid * 32 + k];
        int S = cs;
#pragma unroll
        for (int off = 1; off < 64; off <<= 1) {
            int o = __shfl_down(S, off, 64);
            if (tid + off < 64) S += o;
        }
        unsigned long long bal = __ballot(S >= TOPK);
        int L = 63 - __clzll(bal);
        int accBase = (L < 63) ? __shfl(S, L + 1, 64) : 0;

        int h = (tid < 32) ? (int)hist[L * 32 + tid] : 0;
        int T = h;
#pragma unroll
        for (int off = 1; off < 32; off <<= 1) {
            int o = __shfl_down(T, off, 64);
            if (tid + off < 32) T += o;
        }
        unsigned long long bal2 = __ballot((tid < 32) && (accBase + T >= TOPK));
        int k2 = 63 - __clzll(bal2);
        // suffix strictly above the threshold bucket:
        int accAbove = (k2 < 31) ? (accBase + __shfl(T, k2 + 1, 64)) : accBase;
        if (tid == 0) { s_tb = (unsigned)(L * 32 + k2); s_acc = (unsigned)accAbove; }
    }
    __syncthreads();
    const unsigned int tb  = s_tb;
    const int accAbove     = (int)s_acc;

    // ---- level-2 refinement: histogram next 11 bits within boundary bucket ----
    for (int i = tid; i < 2048; i += 1024) hist[i] = 0;
    __syncthreads();
#pragma unroll
    for (int r = 0; r < 10; ++r) {
        if (r * 1024 + tid < Q) {
            unsigned long long k = kreg[r];
            if ((unsigned int)(k >> 51) == tb)
                atomicAdd(&hist[(unsigned int)(k >> 40) & 0x7FFu], 1u);
        }
    }
    __syncthreads();

    if (tid < 64) {
        const int target2 = TOPK - accAbove;          // >= 1 by construction
        int cs = 0;
#pragma unroll
        for (int k = 0; k < 32; ++k) cs += (int)hist[tid * 32 + k];
        int S = cs;
#pragma unroll
        for (int off = 1; off < 64; off <<= 1) {
            int o = __shfl_down(S, off, 64);
            if (tid + off < 64) S += o;
        }
        unsigned long long bal = __ballot(S >= target2);
        int L = 63 - __clzll(bal);
        int accBase = (L < 63) ? __shfl(S, L + 1, 64) : 0;

        int h = (tid < 32) ? (int)hist[L * 32 + tid] : 0;
        int T = h;
#pragma unroll
        for (int off = 1; off < 32; off <<= 1) {
            int o = __shfl_down(T, off, 64);
            if (tid + off < 32) T += o;
        }
        unsigned long long bal2 = __ballot((tid < 32) && (accBase + T >= target2));
        int k2 = 63 - __clzll(bal2);
        if (tid == 0) s_t2 = (unsigned)(L * 32 + k2);
    }
    __syncthreads();
    const unsigned int t2 = s_t2;

    // ---- collect candidates passing refined threshold (ballot-aggregated) ----
#pragma unroll
    for (int r = 0; r < 10; ++r) {
        int i = r * 1024 + tid;
        unsigned long long k = kreg[r];
        unsigned int b13 = (unsigned int)(k >> 51);
        bool pred = (i < Q) &&
                    ((b13 > tb) ||
                     (b13 == tb && (((unsigned int)(k >> 40)) & 0x7FFu) >= t2));
        unsigned long long mask = __ballot(pred);
        int lane = tid & 63;
        int base;
        if (lane == 0) base = atomicAdd(&s_count, __popcll(mask));
        base = __shfl(base, 0, 64);
        if (pred) {
            int pos = base + __popcll(mask & ((1ull << lane) - 1ull));
            if (pos < 2048) skey[pos] = k;
        }
    }
    __syncthreads();

    const int count = min(s_count, 2048);             // typically ~200-210

    // ---- all-pairs rank scatter (keys unique -> exact descending sort) ----
    for (int i = tid; i < count; i += 1024) {
        unsigned long long ki = skey[i];
        int rank = 0;
        for (int j = 0; j < count; ++j)               // LDS broadcast reads
            rank += (skey[j] > ki) ? 1 : 0;
        if (rank < TOPK) skey2[rank] = ki;            // count >= TOPK guaranteed
    }
    __syncthreads();

    // ---- gather top-200 candidate metadata ----
    if (tid < TOPK) {
        unsigned long long k = skey2[tid];
        int q = (int)(0xFFFFFFFFu - (unsigned int)k);
        cidx[tid] = q;
        ccls[tid] = classes[b * Q + q];
        cx1[tid]  = seg[((long long)b * Q + q) * 2 + 0];
        cx2[tid]  = seg[((long long)b * Q + q) * 2 + 1];
    }
    __syncthreads();

    // ---- suppression bitmatrix: sup[i][w] bit bb -> j = w*64+bb suppressed by i
    for (int w2 = tid; w2 < TOPK * 4; w2 += 1024) {
        int i  = w2 >> 2, ww = w2 & 3;
        int jb = ww * 64;
        float x1 = cx1[i], x2 = cx2[i];
        int   ci = ccls[i];
        unsigned long long bits = 0ull;
        for (int bb = 0; bb < 64; ++bb) {
            int j = jb + bb;
            if (j < TOPK && j > i) {
                float inter = fminf(x2, cx2[j]) - fmaxf(x1, cx1[j]);
                if (inter > 0.0f && ccls[j] == ci)
                    bits |= (1ull << bb);
            }
        }
        sup[i][ww] = bits;
    }
    __syncthreads();

    // ---- greedy scan, wave-parallel: sup matrix register-resident in wave 0.
    // word (p,w) = p*4+w lives at reg g = p/16, lane 4*(p%16)+w.
    if (tid < 64) {
        unsigned long long w[13];
#pragma unroll
        for (int r = 0; r < 13; ++r) {
            int wg = r * 64 + tid;
            w[r] = (wg < TOPK * 4) ? sup[wg >> 2][wg & 3] : 0ull;
        }
        unsigned long long act[4]  = { ~0ull, ~0ull, ~0ull, ~0ull };
        unsigned long long kept[4] = { 0ull, 0ull, 0ull, 0ull };
#pragma unroll
        for (int g = 0; g < 13; ++g) {
#pragma unroll
            for (int s2 = 0; s2 < 16; ++s2) {
                const int p = g * 16 + s2;
                if (p >= TOPK) break;
                if ((act[p >> 6] >> (p & 63)) & 1ull) {   // replicated -> uniform
                    kept[p >> 6] |= 1ull << (p & 63);
                    unsigned long long s0 = __shfl(w[g], 4 * s2 + 0, 64);
                    unsigned long long s1 = __shfl(w[g], 4 * s2 + 1, 64);
                    unsigned long long sv = __shfl(w[g], 4 * s2 + 2, 64);
                    unsigned long long s3 = __shfl(w[g], 4 * s2 + 3, 64);
                    act[0] &= ~s0; act[1] &= ~s1; act[2] &= ~sv; act[3] &= ~s3;
                }
            }
        }
        // parallel compaction of the keep list
        int base0 = 0;
#pragma unroll
        for (int r = 0; r < 4; ++r) {
            int p = r * 64 + tid;
            if (p < TOPK && ((kept[r] >> tid) & 1ull)) {
                int slot = base0 + __popcll(kept[r] & ((1ull << tid) - 1ull));
                keepArr[slot] = cidx[p];
            }
            base0 += __popcll(kept[r]);
        }
        if (tid == 0) s_keepCount = base0;
    }
    __syncthreads();

    const int kc = s_keepCount;
    if (tid < TOPK) {
        out[b * TOPK + tid]       = (tid < kc) ? keepArr[tid] : -1;
        out[(B + b) * TOPK + tid] = 0;
    }
}

extern "C" void kernel_launch(void* const* d_in, const int* in_sizes, int n_in,
                              void* d_out, int out_size, void* d_ws, size_t ws_size,
                              hipStream_t stream)
{
    const float* logits = (const float*)d_in[0];   // [B,Q,C] fp32
    const float* seg    = (const float*)d_in[1];   // [B,Q,2] fp32
    int* out = (int*)d_out;                        // [2B, TOPK] int32

    unsigned long long* keys = (unsigned long long*)d_ws;                 // B*Q*8
    int* classes = (int*)((char*)d_ws + (size_t)B * Q * sizeof(unsigned long long));

    score_kernel<<<(B * Q) / 128, 64, 0, stream>>>(logits, keys, classes);
    nms_kernel<<<B, 1024, 0, stream>>>(keys, classes, seg, out);
}

// Round 5
// 186.069 us; speedup vs baseline: 1.1053x; 1.1053x over previous
//
#include <hip/hip_runtime.h>
#include <math.h>

#define B 32
#define Q 10000
#define C 80
#define TOPK 200

// ---------------------------------------------------------------------------
// Fast double-precision exp for x in [-40, 0]  (identical bits to R2 version)
// ---------------------------------------------------------------------------
__device__ __forceinline__ double fexp(double x) {
    const double L2E   = 1.4426950408889634;      // log2(e)
    const double SHIFT = 6755399441055744.0;      // 1.5 * 2^52
    const double LN2   = 0.6931471805599453;

    double y = x * L2E;
    double t = y + SHIFT;
    union { double d; unsigned long long u; } cv;
    cv.d = t;
    int n = (int)(unsigned int)cv.u;              // low 32 bits = rint(y)
    double f = y - (t - SHIFT);                   // f in [-0.5, 0.5]
    double r = f * LN2;

    double p = 2.755731922398589e-06;             // 1/9!
    p = fma(p, r, 2.4801587301587302e-05);
    p = fma(p, r, 1.984126984126984e-04);
    p = fma(p, r, 1.3888888888888889e-03);
    p = fma(p, r, 8.333333333333333e-03);
    p = fma(p, r, 4.1666666666666664e-02);
    p = fma(p, r, 1.6666666666666666e-01);
    p = fma(p, r, 0.5);
    p = fma(p, r, 1.0);
    p = fma(p, r, 1.0);

    cv.d = p;
    cv.u += ((unsigned long long)(long long)n) << 52;
    return cv.d;
}

// ---------------------------------------------------------------------------
// Kernel 1 v5: register-resident rows, ZERO LDS.
// R3 counters proved the old structure latency-bound (VALUBusy 21%, occ 6.7%):
// single-wave blocks + 20-40 KB LDS capped residency at 2-7 waves/CU against a
// ~10.6 us VALU-issue floor. Fix: each lane loads its own 80-float row into 20
// float4 VGPRs (fully unrolled -> static indexing, no scratch). Stride-320B
// loads amplify L1 transactions 4x but HBM traffic is exact (same-lane line
// reuse hits L1; 20 KB/block << 32 KB L1), and the load phase overlaps the
// ~5200-cycle f64 phase. LDS=0 + launch_bounds(64,4) (VGPR<=128) -> 16
// waves/CU. Numerics: identical sequential max (strict >, j order) and
// identical sequential s += fexp(...) order -> bit-exact.
// ---------------------------------------------------------------------------
__global__ __launch_bounds__(64, 4) void score_kernel(
    const float* __restrict__ logits,
    unsigned long long* __restrict__ keys,
    int* __restrict__ cls_out)
{
    const int t = threadIdx.x;                        // 0..63
    const int grow = blockIdx.x * 64 + t;             // one row per lane
    const float4* __restrict__ src = (const float4*)(logits + (long long)grow * C);

    float4 v4[20];
#pragma unroll
    for (int i = 0; i < 20; ++i)
        v4[i] = src[i];                               // 20 x dwordx4, in flight

    // ---- max pass (identical order: j = 0..79, strict >) ----
    float m = -INFINITY; int idx = 0;
#pragma unroll
    for (int i = 0; i < 20; ++i) {
        float4 v = v4[i];
        if (v.x > m) { m = v.x; idx = 4 * i + 0; }
        if (v.y > m) { m = v.y; idx = 4 * i + 1; }
        if (v.z > m) { m = v.z; idx = 4 * i + 2; }
        if (v.w > m) { m = v.w; idx = 4 * i + 3; }
    }

    // ---- sum pass (identical sequential add order j = 0..79) ----
    const double md = (double)m;
    double s = 0.0;
#pragma unroll
    for (int i = 0; i < 20; ++i) {
        s += fexp((double)v4[i].x - md);
        s += fexp((double)v4[i].y - md);
        s += fexp((double)v4[i].z - md);
        s += fexp((double)v4[i].w - md);
    }

    float sumf  = (float)s;
    float score = 1.0f / sumf;
    unsigned int sbits = __float_as_uint(score);
    unsigned int q = (unsigned)(grow % Q);
    keys[grow]    = ((unsigned long long)sbits << 32) |
                    (unsigned long long)(0xFFFFFFFFu - q);
    cls_out[grow] = idx;
}

// ---------------------------------------------------------------------------
// Kernel 2 (VERBATIM R1 — best measured config): one block (1024 threads)
// per batch. keys -> registers; 13-bit histogram -> wave-0 threshold scan;
// 11-bit refinement histogram on boundary bucket -> wave-0 scan (count
// ~200-210); ballot-aggregated collect; all-pairs rank scatter (exact sort);
// sup bitmatrix; register-resident wave-parallel greedy; compaction.
// ---------------------------------------------------------------------------
__global__ __launch_bounds__(1024) void nms_kernel(
    const unsigned long long* __restrict__ keys,
    const int*   __restrict__ classes,
    const float* __restrict__ seg,
    int*         __restrict__ out)
{
    __shared__ unsigned int        hist[2048];
    __shared__ unsigned long long  skey[2048];      // collected candidates
    __shared__ unsigned long long  skey2[TOPK];     // rank-scattered top-200
    __shared__ int   s_count;
    __shared__ unsigned int s_tb, s_acc, s_t2;
    __shared__ int   cidx[TOPK];
    __shared__ int   ccls[TOPK];
    __shared__ float cx1[TOPK], cx2[TOPK];
    __shared__ unsigned long long sup[TOPK][4];
    __shared__ int   keepArr[TOPK];
    __shared__ int   s_keepCount;

    const int b   = blockIdx.x;
    const int tid = threadIdx.x;
    const unsigned long long* bk = keys + (long long)b * Q;

    // ---- single global pass: keys into registers (10 per thread) ----
    unsigned long long kreg[10];
#pragma unroll
    for (int r = 0; r < 10; ++r) {
        int i = r * 1024 + tid;
        kreg[r] = (i < Q) ? bk[i] : 0ull;
    }

    for (int i = tid; i < 2048; i += 1024) hist[i] = 0;
    if (tid == 0) s_count = 0;
    __syncthreads();

    // ---- histogram of top 13 bits of key (== top 13 bits of score) ----
#pragma unroll
    for (int r = 0; r < 10; ++r) {
        if (r * 1024 + tid < Q)
            atomicAdd(&hist[(unsigned int)(kreg[r] >> 51)], 1u);
    }
    __syncthreads();

    // ---- level-1 threshold: wave-0 two-level suffix scan ----
    if (tid < 64) {
        int cs = 0;
#pragma unroll
        for (int k = 0; k < 32; ++k) cs += (int)hist[tid * 32 + k];
        int S = cs;
#pragma unroll
        for (int off = 1; off < 64; off <<= 1) {
            int o = __shfl_down(S, off, 64);
            if (tid + off < 64) S += o;
        }
        unsigned long long bal = __ballot(S >= TOPK);
        int L = 63 - __clzll(bal);
        int accBase = (L < 63) ? __shfl(S, L + 1, 64) : 0;

        int h = (tid < 32) ? (int)hist[L * 32 + tid] : 0;
        int T = h;
#pragma unroll
        for (int off = 1; off < 32; off <<= 1) {
            int o = __shfl_down(T, off, 64);
            if (tid + off < 32) T += o;
        }
        unsigned long long bal2 = __ballot((tid < 32) && (accBase + T >= TOPK));
        int k2 = 63 - __clzll(bal2);
        // suffix strictly above the threshold bucket:
        int accAbove = (k2 < 31) ? (accBase + __shfl(T, k2 + 1, 64)) : accBase;
        if (tid == 0) { s_tb = (unsigned)(L * 32 + k2); s_acc = (unsigned)accAbove; }
    }
    __syncthreads();
    const unsigned int tb  = s_tb;
    const int accAbove     = (int)s_acc;

    // ---- level-2 refinement: histogram next 11 bits within boundary bucket ----
    for (int i = tid; i < 2048; i += 1024) hist[i] = 0;
    __syncthreads();
#pragma unroll
    for (int r = 0; r < 10; ++r) {
        if (r * 1024 + tid < Q) {
            unsigned long long k = kreg[r];
            if ((unsigned int)(k >> 51) == tb)
                atomicAdd(&hist[(unsigned int)(k >> 40) & 0x7FFu], 1u);
        }
    }
    __syncthreads();

    if (tid < 64) {
        const int target2 = TOPK - accAbove;          // >= 1 by construction
        int cs = 0;
#pragma unroll
        for (int k = 0; k < 32; ++k) cs += (int)hist[tid * 32 + k];
        int S = cs;
#pragma unroll
        for (int off = 1; off < 64; off <<= 1) {
            int o = __shfl_down(S, off, 64);
            if (tid + off < 64) S += o;
        }
        unsigned long long bal = __ballot(S >= target2);
        int L = 63 - __clzll(bal);
        int accBase = (L < 63) ? __shfl(S, L + 1, 64) : 0;

        int h = (tid < 32) ? (int)hist[L * 32 + tid] : 0;
        int T = h;
#pragma unroll
        for (int off = 1; off < 32; off <<= 1) {
            int o = __shfl_down(T, off, 64);
            if (tid + off < 32) T += o;
        }
        unsigned long long bal2 = __ballot((tid < 32) && (accBase + T >= target2));
        int k2 = 63 - __clzll(bal2);
        if (tid == 0) s_t2 = (unsigned)(L * 32 + k2);
    }
    __syncthreads();
    const unsigned int t2 = s_t2;

    // ---- collect candidates passing refined threshold (ballot-aggregated) ----
#pragma unroll
    for (int r = 0; r < 10; ++r) {
        int i = r * 1024 + tid;
        unsigned long long k = kreg[r];
        unsigned int b13 = (unsigned int)(k >> 51);
        bool pred = (i < Q) &&
                    ((b13 > tb) ||
                     (b13 == tb && (((unsigned int)(k >> 40)) & 0x7FFu) >= t2));
        unsigned long long mask = __ballot(pred);
        int lane = tid & 63;
        int base;
        if (lane == 0) base = atomicAdd(&s_count, __popcll(mask));
        base = __shfl(base, 0, 64);
        if (pred) {
            int pos = base + __popcll(mask & ((1ull << lane) - 1ull));
            if (pos < 2048) skey[pos] = k;
        }
    }
    __syncthreads();

    const int count = min(s_count, 2048);             // typically ~200-210

    // ---- all-pairs rank scatter (keys unique -> exact descending sort) ----
    for (int i = tid; i < count; i += 1024) {
        unsigned long long ki = skey[i];
        int rank = 0;
        for (int j = 0; j < count; ++j)               // LDS broadcast reads
            rank += (skey[j] > ki) ? 1 : 0;
        if (rank < TOPK) skey2[rank] = ki;            // count >= TOPK guaranteed
    }
    __syncthreads();

    // ---- gather top-200 candidate metadata ----
    if (tid < TOPK) {
        unsigned long long k = skey2[tid];
        int q = (int)(0xFFFFFFFFu - (unsigned int)k);
        cidx[tid] = q;
        ccls[tid] = classes[b * Q + q];
        cx1[tid]  = seg[((long long)b * Q + q) * 2 + 0];
        cx2[tid]  = seg[((long long)b * Q + q) * 2 + 1];
    }
    __syncthreads();

    // ---- suppression bitmatrix: sup[i][w] bit bb -> j = w*64+bb suppressed by i
    for (int w2 = tid; w2 < TOPK * 4; w2 += 1024) {
        int i  = w2 >> 2, ww = w2 & 3;
        int jb = ww * 64;
        float x1 = cx1[i], x2 = cx2[i];
        int   ci = ccls[i];
        unsigned long long bits = 0ull;
        for (int bb = 0; bb < 64; ++bb) {
            int j = jb + bb;
            if (j < TOPK && j > i) {
                float inter = fminf(x2, cx2[j]) - fmaxf(x1, cx1[j]);
                if (inter > 0.0f && ccls[j] == ci)
                    bits |= (1ull << bb);
            }
        }
        sup[i][ww] = bits;
    }
    __syncthreads();

    // ---- greedy scan, wave-parallel: sup matrix register-resident in wave 0.
    // word (p,w) = p*4+w lives at reg g = p/16, lane 4*(p%16)+w.
    if (tid < 64) {
        unsigned long long w[13];
#pragma unroll
        for (int r = 0; r < 13; ++r) {
            int wg = r * 64 + tid;
            w[r] = (wg < TOPK * 4) ? sup[wg >> 2][wg & 3] : 0ull;
        }
        unsigned long long act[4]  = { ~0ull, ~0ull, ~0ull, ~0ull };
        unsigned long long kept[4] = { 0ull, 0ull, 0ull, 0ull };
#pragma unroll
        for (int g = 0; g < 13; ++g) {
#pragma unroll
            for (int s2 = 0; s2 < 16; ++s2) {
                const int p = g * 16 + s2;
                if (p >= TOPK) break;
                if ((act[p >> 6] >> (p & 63)) & 1ull) {   // replicated -> uniform
                    kept[p >> 6] |= 1ull << (p & 63);
                    unsigned long long s0 = __shfl(w[g], 4 * s2 + 0, 64);
                    unsigned long long s1 = __shfl(w[g], 4 * s2 + 1, 64);
                    unsigned long long sv = __shfl(w[g], 4 * s2 + 2, 64);
                    unsigned long long s3 = __shfl(w[g], 4 * s2 + 3, 64);
                    act[0] &= ~s0; act[1] &= ~s1; act[2] &= ~sv; act[3] &= ~s3;
                }
            }
        }
        // parallel compaction of the keep list
        int base0 = 0;
#pragma unroll
        for (int r = 0; r < 4; ++r) {
            int p = r * 64 + tid;
            if (p < TOPK && ((kept[r] >> tid) & 1ull)) {
                int slot = base0 + __popcll(kept[r] & ((1ull << tid) - 1ull));
                keepArr[slot] = cidx[p];
            }
            base0 += __popcll(kept[r]);
        }
        if (tid == 0) s_keepCount = base0;
    }
    __syncthreads();

    const int kc = s_keepCount;
    if (tid < TOPK) {
        out[b * TOPK + tid]       = (tid < kc) ? keepArr[tid] : -1;
        out[(B + b) * TOPK + tid] = 0;
    }
}

extern "C" void kernel_launch(void* const* d_in, const int* in_sizes, int n_in,
                              void* d_out, int out_size, void* d_ws, size_t ws_size,
                              hipStream_t stream)
{
    const float* logits = (const float*)d_in[0];   // [B,Q,C] fp32
    const float* seg    = (const float*)d_in[1];   // [B,Q,2] fp32
    int* out = (int*)d_out;                        // [2B, TOPK] int32

    unsigned long long* keys = (unsigned long long*)d_ws;                 // B*Q*8
    int* classes = (int*)((char*)d_ws + (size_t)B * Q * sizeof(unsigned long long));

    score_kernel<<<(B * Q) / 64, 64, 0, stream>>>(logits, keys, classes);
    nms_kernel<<<B, 1024, 0, stream>>>(keys, classes, seg, out);
}

// Round 6
// 185.873 us; speedup vs baseline: 1.1064x; 1.0011x over previous
//
#include <hip/hip_runtime.h>
#include <math.h>

#define B 32
#define Q 10000
#define C 80
#define TOPK 200

// ---------------------------------------------------------------------------
// Fast double-precision exp for x in [-40, 0]  (identical bits to R2 version)
// ---------------------------------------------------------------------------
__device__ __forceinline__ double fexp(double x) {
    const double L2E   = 1.4426950408889634;      // log2(e)
    const double SHIFT = 6755399441055744.0;      // 1.5 * 2^52
    const double LN2   = 0.6931471805599453;

    double y = x * L2E;
    double t = y + SHIFT;
    union { double d; unsigned long long u; } cv;
    cv.d = t;
    int n = (int)(unsigned int)cv.u;              // low 32 bits = rint(y)
    double f = y - (t - SHIFT);                   // f in [-0.5, 0.5]
    double r = f * LN2;

    double p = 2.755731922398589e-06;             // 1/9!
    p = fma(p, r, 2.4801587301587302e-05);
    p = fma(p, r, 1.984126984126984e-04);
    p = fma(p, r, 1.3888888888888889e-03);
    p = fma(p, r, 8.333333333333333e-03);
    p = fma(p, r, 4.1666666666666664e-02);
    p = fma(p, r, 1.6666666666666666e-01);
    p = fma(p, r, 0.5);
    p = fma(p, r, 1.0);
    p = fma(p, r, 1.0);

    cv.d = p;
    cv.u += ((unsigned long long)(long long)n) << 52;
    return cv.d;
}

// ---------------------------------------------------------------------------
// Kernel 1 v6: register-resident rows, ZERO LDS — single-variable change vs
// R5: __launch_bounds__(64, 2) instead of (64, 4).
// R5's (64,4) forced VGPR<=128 against a ~150-VGPR demand (v4[20]=80 + f64
// poly temps + addrs; R3's unbounded sibling compiled to 132) -> likely
// scratch spills in the fexp loop, pinning score at ~50us. (64,2) caps at
// 256 VGPR: no spill, still 2-3 waves/SIMD (8-12 waves/CU, LDS=0).
// Per-lane row loads are contiguous 320B (5 cache lines/lane, each line
// consumed fully by 4 consecutive float4 loads of the same lane -> exact
// HBM traffic, L1 absorbs the 4x request amplification).
// Numerics bit-exact: identical strict-> max order, identical sequential
// f64 add chain.
// ---------------------------------------------------------------------------
__global__ __launch_bounds__(64, 2) void score_kernel(
    const float* __restrict__ logits,
    unsigned long long* __restrict__ keys,
    int* __restrict__ cls_out)
{
    const int t = threadIdx.x;                        // 0..63
    const int grow = blockIdx.x * 64 + t;             // one row per lane
    const float4* __restrict__ src = (const float4*)(logits + (long long)grow * C);

    float4 v4[20];
#pragma unroll
    for (int i = 0; i < 20; ++i)
        v4[i] = src[i];                               // 20 x dwordx4, in flight

    // ---- max pass (identical order: j = 0..79, strict >) ----
    float m = -INFINITY; int idx = 0;
#pragma unroll
    for (int i = 0; i < 20; ++i) {
        float4 v = v4[i];
        if (v.x > m) { m = v.x; idx = 4 * i + 0; }
        if (v.y > m) { m = v.y; idx = 4 * i + 1; }
        if (v.z > m) { m = v.z; idx = 4 * i + 2; }
        if (v.w > m) { m = v.w; idx = 4 * i + 3; }
    }

    // ---- sum pass (identical sequential add order j = 0..79) ----
    const double md = (double)m;
    double s = 0.0;
#pragma unroll
    for (int i = 0; i < 20; ++i) {
        s += fexp((double)v4[i].x - md);
        s += fexp((double)v4[i].y - md);
        s += fexp((double)v4[i].z - md);
        s += fexp((double)v4[i].w - md);
    }

    float sumf  = (float)s;
    float score = 1.0f / sumf;
    unsigned int sbits = __float_as_uint(score);
    unsigned int q = (unsigned)(grow % Q);
    keys[grow]    = ((unsigned long long)sbits << 32) |
                    (unsigned long long)(0xFFFFFFFFu - q);
    cls_out[grow] = idx;
}

// ---------------------------------------------------------------------------
// Kernel 2 (VERBATIM R1 — best measured config): one block (1024 threads)
// per batch. keys -> registers; 13-bit histogram -> wave-0 threshold scan;
// 11-bit refinement histogram on boundary bucket -> wave-0 scan (count
// ~200-210); ballot-aggregated collect; all-pairs rank scatter (exact sort);
// sup bitmatrix; register-resident wave-parallel greedy; compaction.
// ---------------------------------------------------------------------------
__global__ __launch_bounds__(1024) void nms_kernel(
    const unsigned long long* __restrict__ keys,
    const int*   __restrict__ classes,
    const float* __restrict__ seg,
    int*         __restrict__ out)
{
    __shared__ unsigned int        hist[2048];
    __shared__ unsigned long long  skey[2048];      // collected candidates
    __shared__ unsigned long long  skey2[TOPK];     // rank-scattered top-200
    __shared__ int   s_count;
    __shared__ unsigned int s_tb, s_acc, s_t2;
    __shared__ int   cidx[TOPK];
    __shared__ int   ccls[TOPK];
    __shared__ float cx1[TOPK], cx2[TOPK];
    __shared__ unsigned long long sup[TOPK][4];
    __shared__ int   keepArr[TOPK];
    __shared__ int   s_keepCount;

    const int b   = blockIdx.x;
    const int tid = threadIdx.x;
    const unsigned long long* bk = keys + (long long)b * Q;

    // ---- single global pass: keys into registers (10 per thread) ----
    unsigned long long kreg[10];
#pragma unroll
    for (int r = 0; r < 10; ++r) {
        int i = r * 1024 + tid;
        kreg[r] = (i < Q) ? bk[i] : 0ull;
    }

    for (int i = tid; i < 2048; i += 1024) hist[i] = 0;
    if (tid == 0) s_count = 0;
    __syncthreads();

    // ---- histogram of top 13 bits of key (== top 13 bits of score) ----
#pragma unroll
    for (int r = 0; r < 10; ++r) {
        if (r * 1024 + tid < Q)
            atomicAdd(&hist[(unsigned int)(kreg[r] >> 51)], 1u);
    }
    __syncthreads();

    // ---- level-1 threshold: wave-0 two-level suffix scan ----
    if (tid < 64) {
        int cs = 0;
#pragma unroll
        for (int k = 0; k < 32; ++k) cs += (int)hist[tid * 32 + k];
        int S = cs;
#pragma unroll
        for (int off = 1; off < 64; off <<= 1) {
            int o = __shfl_down(S, off, 64);
            if (tid + off < 64) S += o;
        }
        unsigned long long bal = __ballot(S >= TOPK);
        int L = 63 - __clzll(bal);
        int accBase = (L < 63) ? __shfl(S, L + 1, 64) : 0;

        int h = (tid < 32) ? (int)hist[L * 32 + tid] : 0;
        int T = h;
#pragma unroll
        for (int off = 1; off < 32; off <<= 1) {
            int o = __shfl_down(T, off, 64);
            if (tid + off < 32) T += o;
        }
        unsigned long long bal2 = __ballot((tid < 32) && (accBase + T >= TOPK));
        int k2 = 63 - __clzll(bal2);
        // suffix strictly above the threshold bucket:
        int accAbove = (k2 < 31) ? (accBase + __shfl(T, k2 + 1, 64)) : accBase;
        if (tid == 0) { s_tb = (unsigned)(L * 32 + k2); s_acc = (unsigned)accAbove; }
    }
    __syncthreads();
    const unsigned int tb  = s_tb;
    const int accAbove     = (int)s_acc;

    // ---- level-2 refinement: histogram next 11 bits within boundary bucket ----
    for (int i = tid; i < 2048; i += 1024) hist[i] = 0;
    __syncthreads();
#pragma unroll
    for (int r = 0; r < 10; ++r) {
        if (r * 1024 + tid < Q) {
            unsigned long long k = kreg[r];
            if ((unsigned int)(k >> 51) == tb)
                atomicAdd(&hist[(unsigned int)(k >> 40) & 0x7FFu], 1u);
        }
    }
    __syncthreads();

    if (tid < 64) {
        const int target2 = TOPK - accAbove;          // >= 1 by construction
        int cs = 0;
#pragma unroll
        for (int k = 0; k < 32; ++k) cs += (int)hist[tid * 32 + k];
        int S = cs;
#pragma unroll
        for (int off = 1; off < 64; off <<= 1) {
            int o = __shfl_down(S, off, 64);
            if (tid + off < 64) S += o;
        }
        unsigned long long bal = __ballot(S >= target2);
        int L = 63 - __clzll(bal);
        int accBase = (L < 63) ? __shfl(S, L + 1, 64) : 0;

        int h = (tid < 32) ? (int)hist[L * 32 + tid] : 0;
        int T = h;
#pragma unroll
        for (int off = 1; off < 32; off <<= 1) {
            int o = __shfl_down(T, off, 64);
            if (tid + off < 32) T += o;
        }
        unsigned long long bal2 = __ballot((tid < 32) && (accBase + T >= target2));
        int k2 = 63 - __clzll(bal2);
        if (tid == 0) s_t2 = (unsigned)(L * 32 + k2);
    }
    __syncthreads();
    const unsigned int t2 = s_t2;

    // ---- collect candidates passing refined threshold (ballot-aggregated) ----
#pragma unroll
    for (int r = 0; r < 10; ++r) {
        int i = r * 1024 + tid;
        unsigned long long k = kreg[r];
        unsigned int b13 = (unsigned int)(k >> 51);
        bool pred = (i < Q) &&
                    ((b13 > tb) ||
                     (b13 == tb && (((unsigned int)(k >> 40)) & 0x7FFu) >= t2));
        unsigned long long mask = __ballot(pred);
        int lane = tid & 63;
        int base;
        if (lane == 0) base = atomicAdd(&s_count, __popcll(mask));
        base = __shfl(base, 0, 64);
        if (pred) {
            int pos = base + __popcll(mask & ((1ull << lane) - 1ull));
            if (pos < 2048) skey[pos] = k;
        }
    }
    __syncthreads();

    const int count = min(s_count, 2048);             // typically ~200-210

    // ---- all-pairs rank scatter (keys unique -> exact descending sort) ----
    for (int i = tid; i < count; i += 1024) {
        unsigned long long ki = skey[i];
        int rank = 0;
        for (int j = 0; j < count; ++j)               // LDS broadcast reads
            rank += (skey[j] > ki) ? 1 : 0;
        if (rank < TOPK) skey2[rank] = ki;            // count >= TOPK guaranteed
    }
    __syncthreads();

    // ---- gather top-200 candidate metadata ----
    if (tid < TOPK) {
        unsigned long long k = skey2[tid];
        int q = (int)(0xFFFFFFFFu - (unsigned int)k);
        cidx[tid] = q;
        ccls[tid] = classes[b * Q + q];
        cx1[tid]  = seg[((long long)b * Q + q) * 2 + 0];
        cx2[tid]  = seg[((long long)b * Q + q) * 2 + 1];
    }
    __syncthreads();

    // ---- suppression bitmatrix: sup[i][w] bit bb -> j = w*64+bb suppressed by i
    for (int w2 = tid; w2 < TOPK * 4; w2 += 1024) {
        int i  = w2 >> 2, ww = w2 & 3;
        int jb = ww * 64;
        float x1 = cx1[i], x2 = cx2[i];
        int   ci = ccls[i];
        unsigned long long bits = 0ull;
        for (int bb = 0; bb < 64; ++bb) {
            int j = jb + bb;
            if (j < TOPK && j > i) {
                float inter = fminf(x2, cx2[j]) - fmaxf(x1, cx1[j]);
                if (inter > 0.0f && ccls[j] == ci)
                    bits |= (1ull << bb);
            }
        }
        sup[i][ww] = bits;
    }
    __syncthreads();

    // ---- greedy scan, wave-parallel: sup matrix register-resident in wave 0.
    // word (p,w) = p*4+w lives at reg g = p/16, lane 4*(p%16)+w.
    if (tid < 64) {
        unsigned long long w[13];
#pragma unroll
        for (int r = 0; r < 13; ++r) {
            int wg = r * 64 + tid;
            w[r] = (wg < TOPK * 4) ? sup[wg >> 2][wg & 3] : 0ull;
        }
        unsigned long long act[4]  = { ~0ull, ~0ull, ~0ull, ~0ull };
        unsigned long long kept[4] = { 0ull, 0ull, 0ull, 0ull };
#pragma unroll
        for (int g = 0; g < 13; ++g) {
#pragma unroll
            for (int s2 = 0; s2 < 16; ++s2) {
                const int p = g * 16 + s2;
                if (p >= TOPK) break;
                if ((act[p >> 6] >> (p & 63)) & 1ull) {   // replicated -> uniform
                    kept[p >> 6] |= 1ull << (p & 63);
                    unsigned long long s0 = __shfl(w[g], 4 * s2 + 0, 64);
                    unsigned long long s1 = __shfl(w[g], 4 * s2 + 1, 64);
                    unsigned long long sv = __shfl(w[g], 4 * s2 + 2, 64);
                    unsigned long long s3 = __shfl(w[g], 4 * s2 + 3, 64);
                    act[0] &= ~s0; act[1] &= ~s1; act[2] &= ~sv; act[3] &= ~s3;
                }
            }
        }
        // parallel compaction of the keep list
        int base0 = 0;
#pragma unroll
        for (int r = 0; r < 4; ++r) {
            int p = r * 64 + tid;
            if (p < TOPK && ((kept[r] >> tid) & 1ull)) {
                int slot = base0 + __popcll(kept[r] & ((1ull << tid) - 1ull));
                keepArr[slot] = cidx[p];
            }
            base0 += __popcll(kept[r]);
        }
        if (tid == 0) s_keepCount = base0;
    }
    __syncthreads();

    const int kc = s_keepCount;
    if (tid < TOPK) {
        out[b * TOPK + tid]       = (tid < kc) ? keepArr[tid] : -1;
        out[(B + b) * TOPK + tid] = 0;
    }
}

extern "C" void kernel_launch(void* const* d_in, const int* in_sizes, int n_in,
                              void* d_out, int out_size, void* d_ws, size_t ws_size,
                              hipStream_t stream)
{
    const float* logits = (const float*)d_in[0];   // [B,Q,C] fp32
    const float* seg    = (const float*)d_in[1];   // [B,Q,2] fp32
    int* out = (int*)d_out;                        // [2B, TOPK] int32

    unsigned long long* keys = (unsigned long long*)d_ws;                 // B*Q*8
    int* classes = (int*)((char*)d_ws + (size_t)B * Q * sizeof(unsigned long long));

    score_kernel<<<(B * Q) / 64, 64, 0, stream>>>(logits, keys, classes);
    nms_kernel<<<B, 1024, 0, stream>>>(keys, classes, seg, out);
}

// Round 7
// 185.246 us; speedup vs baseline: 1.1102x; 1.0034x over previous
//
#include <hip/hip_runtime.h>
#include <math.h>

#define B 32
#define Q 10000
#define C 80
#define TOPK 200

// ---------------------------------------------------------------------------
// Fast double-precision exp for x in [-40, 0]  (identical bits to R2 version)
// ---------------------------------------------------------------------------
__device__ __forceinline__ double fexp(double x) {
    const double L2E   = 1.4426950408889634;      // log2(e)
    const double SHIFT = 6755399441055744.0;      // 1.5 * 2^52
    const double LN2   = 0.6931471805599453;

    double y = x * L2E;
    double t = y + SHIFT;
    union { double d; unsigned long long u; } cv;
    cv.d = t;
    int n = (int)(unsigned int)cv.u;              // low 32 bits = rint(y)
    double f = y - (t - SHIFT);                   // f in [-0.5, 0.5]
    double r = f * LN2;

    double p = 2.755731922398589e-06;             // 1/9!
    p = fma(p, r, 2.4801587301587302e-05);
    p = fma(p, r, 1.984126984126984e-04);
    p = fma(p, r, 1.3888888888888889e-03);
    p = fma(p, r, 8.333333333333333e-03);
    p = fma(p, r, 4.1666666666666664e-02);
    p = fma(p, r, 1.6666666666666666e-01);
    p = fma(p, r, 0.5);
    p = fma(p, r, 1.0);
    p = fma(p, r, 1.0);

    cv.d = p;
    cv.u += ((unsigned long long)(long long)n) << 52;
    return cv.d;
}

// ---------------------------------------------------------------------------
// Kernel 1 (UNCHANGED from R6 — best measured): register-resident rows, zero
// LDS, __launch_bounds__(64,2) so no forced spills. Bit-exact numerics.
// ---------------------------------------------------------------------------
__global__ __launch_bounds__(64, 2) void score_kernel(
    const float* __restrict__ logits,
    unsigned long long* __restrict__ keys,
    int* __restrict__ cls_out)
{
    const int t = threadIdx.x;                        // 0..63
    const int grow = blockIdx.x * 64 + t;             // one row per lane
    const float4* __restrict__ src = (const float4*)(logits + (long long)grow * C);

    float4 v4[20];
#pragma unroll
    for (int i = 0; i < 20; ++i)
        v4[i] = src[i];                               // 20 x dwordx4, in flight

    // ---- max pass (identical order: j = 0..79, strict >) ----
    float m = -INFINITY; int idx = 0;
#pragma unroll
    for (int i = 0; i < 20; ++i) {
        float4 v = v4[i];
        if (v.x > m) { m = v.x; idx = 4 * i + 0; }
        if (v.y > m) { m = v.y; idx = 4 * i + 1; }
        if (v.z > m) { m = v.z; idx = 4 * i + 2; }
        if (v.w > m) { m = v.w; idx = 4 * i + 3; }
    }

    // ---- sum pass (identical sequential add order j = 0..79) ----
    const double md = (double)m;
    double s = 0.0;
#pragma unroll
    for (int i = 0; i < 20; ++i) {
        s += fexp((double)v4[i].x - md);
        s += fexp((double)v4[i].y - md);
        s += fexp((double)v4[i].z - md);
        s += fexp((double)v4[i].w - md);
    }

    float sumf  = (float)s;
    float score = 1.0f / sumf;
    unsigned int sbits = __float_as_uint(score);
    unsigned int q = (unsigned)(grow % Q);
    keys[grow]    = ((unsigned long long)sbits << 32) |
                    (unsigned long long)(0xFFFFFFFFu - q);
    cls_out[grow] = idx;
}

// ---------------------------------------------------------------------------
// Kernel 2 v6: one block (1024 threads) per batch.
// R6 counters: nms = 92 us dominant, VGPR=60 at 1024 thr -> kreg[10] almost
// certainly spilled to scratch; plus 3 full Q-passes + 2 scans + 12 barriers.
// Changes: (a) NO kreg — stream keys from L2 each pass (removes spill);
// (b) single 4096-bucket histogram (bucket = key>>50, monotonic; 5 mantissa
// bits -> boundary bucket ~300) -> NO refinement pass in the common case
// (guarded fallback only if candidates would overflow skey). Collect /
// rank-scatter / bitmatrix / greedy verbatim from R1 (proven exact).
// ---------------------------------------------------------------------------
__global__ __launch_bounds__(1024) void nms_kernel(
    const unsigned long long* __restrict__ keys,
    const int*   __restrict__ classes,
    const float* __restrict__ seg,
    int*         __restrict__ out)
{
    __shared__ unsigned int        hist[4096];      // 16 KB
    __shared__ unsigned long long  skey[2048];      // collected candidates
    __shared__ unsigned long long  skey2[TOPK];     // rank-scattered top-200
    __shared__ int   s_count;
    __shared__ unsigned int s_tb, s_t2;
    __shared__ int   s_need2;
    __shared__ int   cidx[TOPK];
    __shared__ int   ccls[TOPK];
    __shared__ float cx1[TOPK], cx2[TOPK];
    __shared__ unsigned long long sup[TOPK][4];
    __shared__ int   keepArr[TOPK];
    __shared__ int   s_keepCount;

    const int b   = blockIdx.x;
    const int tid = threadIdx.x;
    const unsigned long long* bk = keys + (long long)b * Q;

    for (int i = tid; i < 4096; i += 1024) hist[i] = 0;
    if (tid == 0) s_count = 0;
    __syncthreads();

    // ---- single histogram pass: bucket = top 14 bits of score bits ----
    // score in (0,1] -> sbits <= 0x3F800000 -> bucket = sbits>>18 <= 4064
#pragma unroll
    for (int r = 0; r < 10; ++r) {
        int i = r * 1024 + tid;
        if (i < Q)
            atomicAdd(&hist[(unsigned int)(bk[i] >> 50)], 1u);
    }
    __syncthreads();

    // ---- threshold: wave-0 two-level (64x64) suffix scan over 4096 ----
    if (tid < 64) {
        int cs = 0;
        for (int k = 0; k < 64; ++k) cs += (int)hist[tid * 64 + k];
        int S = cs;                                   // suffix-inclusive chunks
#pragma unroll
        for (int off = 1; off < 64; off <<= 1) {
            int o = __shfl_down(S, off, 64);
            if (tid + off < 64) S += o;
        }
        unsigned long long bal = __ballot(S >= TOPK); // bit0 set (S_0 = Q)
        int L = 63 - __clzll(bal);                    // chunk holding threshold
        int accBase = (L < 63) ? __shfl(S, L + 1, 64) : 0;

        int T = (int)hist[L * 64 + tid];              // all 64 sub-buckets
#pragma unroll
        for (int off = 1; off < 64; off <<= 1) {
            int o = __shfl_down(T, off, 64);
            if (tid + off < 64) T += o;
        }
        unsigned long long bal2 = __ballot(accBase + T >= TOPK);
        int k2 = 63 - __clzll(bal2);
        int accAbove = (k2 < 63) ? (accBase + __shfl(T, k2 + 1, 64)) : accBase;
        if (tid == 0) {
            int tbq = L * 64 + k2;
            int cand = accAbove + (int)hist[tbq];     // total candidates
            s_tb = (unsigned)tbq;
            s_t2 = 0u;                                // default: no refinement
            s_need2 = (cand > 2048) ? (TOPK - accAbove) : 0;  // fallback target
        }
    }
    __syncthreads();
    const unsigned int tb = s_tb;

    // ---- refinement fallback (expected never: boundary bucket ~300) ----
    if (s_need2) {
        for (int i = tid; i < 2048; i += 1024) hist[i] = 0;
        __syncthreads();
#pragma unroll
        for (int r = 0; r < 10; ++r) {
            int i = r * 1024 + tid;
            if (i < Q) {
                unsigned long long k = bk[i];
                if ((unsigned int)(k >> 50) == tb)
                    atomicAdd(&hist[(unsigned int)(k >> 39) & 0x7FFu], 1u);
            }
        }
        __syncthreads();

        if (tid < 64) {
            const int target2 = s_need2;              // TOPK - accAbove >= 1
            int cs = 0;
#pragma unroll
            for (int k = 0; k < 32; ++k) cs += (int)hist[tid * 32 + k];
            int S = cs;
#pragma unroll
            for (int off = 1; off < 64; off <<= 1) {
                int o = __shfl_down(S, off, 64);
                if (tid + off < 64) S += o;
            }
            unsigned long long bal = __ballot(S >= target2);
            int L = 63 - __clzll(bal);
            int accBase = (L < 63) ? __shfl(S, L + 1, 64) : 0;

            int h = (tid < 32) ? (int)hist[L * 32 + tid] : 0;
            int T = h;
#pragma unroll
            for (int off = 1; off < 32; off <<= 1) {
                int o = __shfl_down(T, off, 64);
                if (tid + off < 32) T += o;
            }
            unsigned long long bal2 = __ballot((tid < 32) && (accBase + T >= target2));
            int k2 = 63 - __clzll(bal2);
            if (tid == 0) s_t2 = (unsigned)(L * 32 + k2);
        }
        __syncthreads();
    }
    const unsigned int t2 = s_t2;                     // 0 when no refinement

    // ---- collect candidates (ballot-aggregated; order irrelevant) ----
#pragma unroll
    for (int r = 0; r < 10; ++r) {
        int i = r * 1024 + tid;
        unsigned long long k = (i < Q) ? bk[i] : 0ull;
        unsigned int bkt = (unsigned int)(k >> 50);
        bool pred = (i < Q) &&
                    ((bkt > tb) ||
                     (bkt == tb && (((unsigned int)(k >> 39)) & 0x7FFu) >= t2));
        unsigned long long mask = __ballot(pred);
        int lane = tid & 63;
        int base;
        if (lane == 0) base = atomicAdd(&s_count, __popcll(mask));
        base = __shfl(base, 0, 64);
        if (pred) {
            int pos = base + __popcll(mask & ((1ull << lane) - 1ull));
            if (pos < 2048) skey[pos] = k;
        }
    }
    __syncthreads();

    const int count = min(s_count, 2048);             // typically ~300-500

    // ---- all-pairs rank scatter (keys unique -> exact descending sort) ----
    for (int i = tid; i < count; i += 1024) {
        unsigned long long ki = skey[i];
        int rank = 0;
        for (int j = 0; j < count; ++j)               // LDS broadcast reads
            rank += (skey[j] > ki) ? 1 : 0;
        if (rank < TOPK) skey2[rank] = ki;            // count >= TOPK guaranteed
    }
    __syncthreads();

    // ---- gather top-200 candidate metadata ----
    if (tid < TOPK) {
        unsigned long long k = skey2[tid];
        int q = (int)(0xFFFFFFFFu - (unsigned int)k);
        cidx[tid] = q;
        ccls[tid] = classes[b * Q + q];
        cx1[tid]  = seg[((long long)b * Q + q) * 2 + 0];
        cx2[tid]  = seg[((long long)b * Q + q) * 2 + 1];
    }
    __syncthreads();

    // ---- suppression bitmatrix: sup[i][w] bit bb -> j = w*64+bb suppressed by i
    for (int w2 = tid; w2 < TOPK * 4; w2 += 1024) {
        int i  = w2 >> 2, ww = w2 & 3;
        int jb = ww * 64;
        float x1 = cx1[i], x2 = cx2[i];
        int   ci = ccls[i];
        unsigned long long bits = 0ull;
        for (int bb = 0; bb < 64; ++bb) {
            int j = jb + bb;
            if (j < TOPK && j > i) {
                float inter = fminf(x2, cx2[j]) - fmaxf(x1, cx1[j]);
                if (inter > 0.0f && ccls[j] == ci)
                    bits |= (1ull << bb);
            }
        }
        sup[i][ww] = bits;
    }
    __syncthreads();

    // ---- greedy scan, wave-parallel: sup matrix register-resident in wave 0.
    // word (p,w) = p*4+w lives at reg g = p/16, lane 4*(p%16)+w.
    if (tid < 64) {
        unsigned long long w[13];
#pragma unroll
        for (int r = 0; r < 13; ++r) {
            int wg = r * 64 + tid;
            w[r] = (wg < TOPK * 4) ? sup[wg >> 2][wg & 3] : 0ull;
        }
        unsigned long long act[4]  = { ~0ull, ~0ull, ~0ull, ~0ull };
        unsigned long long kept[4] = { 0ull, 0ull, 0ull, 0ull };
#pragma unroll
        for (int g = 0; g < 13; ++g) {
#pragma unroll
            for (int s2 = 0; s2 < 16; ++s2) {
                const int p = g * 16 + s2;
                if (p >= TOPK) break;
                if ((act[p >> 6] >> (p & 63)) & 1ull) {   // replicated -> uniform
                    kept[p >> 6] |= 1ull << (p & 63);
                    unsigned long long s0 = __shfl(w[g], 4 * s2 + 0, 64);
                    unsigned long long s1 = __shfl(w[g], 4 * s2 + 1, 64);
                    unsigned long long sv = __shfl(w[g], 4 * s2 + 2, 64);
                    unsigned long long s3 = __shfl(w[g], 4 * s2 + 3, 64);
                    act[0] &= ~s0; act[1] &= ~s1; act[2] &= ~sv; act[3] &= ~s3;
                }
            }
        }
        // parallel compaction of the keep list
        int base0 = 0;
#pragma unroll
        for (int r = 0; r < 4; ++r) {
            int p = r * 64 + tid;
            if (p < TOPK && ((kept[r] >> tid) & 1ull)) {
                int slot = base0 + __popcll(kept[r] & ((1ull << tid) - 1ull));
                keepArr[slot] = cidx[p];
            }
            base0 += __popcll(kept[r]);
        }
        if (tid == 0) s_keepCount = base0;
    }
    __syncthreads();

    const int kc = s_keepCount;
    if (tid < TOPK) {
        out[b * TOPK + tid]       = (tid < kc) ? keepArr[tid] : -1;
        out[(B + b) * TOPK + tid] = 0;
    }
}

extern "C" void kernel_launch(void* const* d_in, const int* in_sizes, int n_in,
                              void* d_out, int out_size, void* d_ws, size_t ws_size,
                              hipStream_t stream)
{
    const float* logits = (const float*)d_in[0];   // [B,Q,C] fp32
    const float* seg    = (const float*)d_in[1];   // [B,Q,2] fp32
    int* out = (int*)d_out;                        // [2B, TOPK] int32

    unsigned long long* keys = (unsigned long long*)d_ws;                 // B*Q*8
    int* classes = (int*)((char*)d_ws + (size_t)B * Q * sizeof(unsigned long long));

    score_kernel<<<(B * Q) / 64, 64, 0, stream>>>(logits, keys, classes);
    nms_kernel<<<B, 1024, 0, stream>>>(keys, classes, seg, out);
}